// Round 12
// baseline (1137.873 us; speedup 1.0000x reference)
//
#include <hip/hip_runtime.h>
#include <math.h>

#define NN 10000
#define NFEAT 512
#define NHID 256
#define NCLASS 40
#define MAXDEG 64

typedef __attribute__((ext_vector_type(8))) short short8v;   // 8 bf16 (4 VGPR)
typedef __attribute__((ext_vector_type(4))) float floatx4;   // MFMA acc

static __device__ __forceinline__ unsigned short bf16_rne(float f) {
    unsigned u = __builtin_bit_cast(unsigned, f);
    u += 0x7fffu + ((u >> 16) & 1u);
    return (unsigned short)(u >> 16);
}
static __device__ __forceinline__ float bf16_f32(unsigned short h) {
    unsigned u = ((unsigned)h) << 16;
    return __builtin_bit_cast(float, u);
}

// ---------------------------------------------------------------------------
// prep: fused one-shot setup (packs + x split + deg zero). Layout:
//   P[((ks*NTOT+ct)*64+lane)*8+j] = B[k][c],
//   k = ks*32 + 8*(lane>>4) + j,  c = ct*16 + (lane&15)
// ---------------------------------------------------------------------------
__global__ __launch_bounds__(256) void prep(const float* __restrict__ EW,
                                            const float* __restrict__ W,
                                            const float* __restrict__ DW,
                                            const float* __restrict__ x,
                                            unsigned short* __restrict__ PEh,
                                            unsigned short* __restrict__ PEl,
                                            unsigned short* __restrict__ PWh,
                                            unsigned short* __restrict__ PWl,
                                            unsigned short* __restrict__ PDh,
                                            unsigned short* __restrict__ PDl,
                                            unsigned short* __restrict__ xh,
                                            unsigned short* __restrict__ xl,
                                            int* __restrict__ deg) {
    int b = blockIdx.x;
    if (b < 512) {                                  // enc pack
        int idx = b * 256 + threadIdx.x;
        int j = idx & 7, lane = (idx >> 3) & 63;
        int ctks = idx >> 9;
        int ct = ctks & 15, ks = ctks >> 4;
        int k = ks * 32 + ((lane >> 4) << 3) + j;
        int c = ct * 16 + (lane & 15);
        float w = EW[(size_t)c * NFEAT + k];
        unsigned short h = bf16_rne(w);
        PEh[idx] = h;
        PEl[idx] = bf16_rne(w - bf16_f32(h));
    } else if (b < 768) {                           // layer pack (0.25*(W+W^T))
        int idx = (b - 512) * 256 + threadIdx.x;
        int j = idx & 7, lane = (idx >> 3) & 63;
        int ctks = idx >> 9;
        int ct = ctks & 15, ks = ctks >> 4;
        int k = ks * 32 + ((lane >> 4) << 3) + j;
        int c = ct * 16 + (lane & 15);
        float w = 0.25f * (W[k * NHID + c] + W[c * NHID + k]);
        unsigned short h = bf16_rne(w);
        PWh[idx] = h;
        PWl[idx] = bf16_rne(w - bf16_f32(h));
    } else if (b < 816) {                           // dec pack
        int idx = (b - 768) * 256 + threadIdx.x;    // 12288
        int j = idx & 7, lane = (idx >> 3) & 63;
        int ctks = idx >> 9;
        int ct = ctks % 3, ks = ctks / 3;
        int k = ks * 32 + ((lane >> 4) << 3) + j;
        int c = ct * 16 + (lane & 15);
        float w = (c < NCLASS) ? DW[(size_t)c * NHID + k] : 0.f;
        unsigned short h = bf16_rne(w);
        PDh[idx] = h;
        PDl[idx] = bf16_rne(w - bf16_f32(h));
    } else if (b < 5816) {                          // split x (f32 -> bf16 hi/lo)
        int i = (b - 816) * 256 + threadIdx.x;      // 1,280,000 float4
        float4 v = ((const float4*)x)[i];
        ushort4 h, l;
        h.x = bf16_rne(v.x); l.x = bf16_rne(v.x - bf16_f32(h.x));
        h.y = bf16_rne(v.y); l.y = bf16_rne(v.y - bf16_f32(h.y));
        h.z = bf16_rne(v.z); l.z = bf16_rne(v.z - bf16_f32(h.z));
        h.w = bf16_rne(v.w); l.w = bf16_rne(v.w - bf16_f32(h.w));
        ((ushort4*)xh)[i] = h;
        ((ushort4*)xl)[i] = l;
    } else {                                        // zero deg
        int i = (b - 5816) * 256 + threadIdx.x;
        if (i < NN) deg[i] = 0;
    }
}

// ---------------------------------------------------------------------------
// scan_upper: symmetric A -> scan j > i only (200 MB), mirror edges via
// atomic index reservation.
// ---------------------------------------------------------------------------
__global__ __launch_bounds__(256) void scan_upper(const float* __restrict__ A,
                                                  int* __restrict__ cols,
                                                  int* __restrict__ deg) {
    int wave = threadIdx.x >> 6;
    int lane = threadIdx.x & 63;
    int row = blockIdx.x * 4 + wave;
    if (row >= NN) return;
    const float4* Arow = (const float4*)(A + (size_t)row * NN);
    int qstart = (row + 1) >> 2;
    for (int q = qstart + lane; q < NN / 4; q += 64) {
        float4 v = Arow[q];
        int jb = 4 * q;
        if (v.x != 0.f && jb + 0 > row) {
            int p = atomicAdd(&deg[row], 1); if (p < MAXDEG) cols[(size_t)row * MAXDEG + p] = jb;
            int m = atomicAdd(&deg[jb], 1);  if (m < MAXDEG) cols[(size_t)jb * MAXDEG + m] = row;
        }
        if (v.y != 0.f && jb + 1 > row) {
            int j = jb + 1;
            int p = atomicAdd(&deg[row], 1); if (p < MAXDEG) cols[(size_t)row * MAXDEG + p] = j;
            int m = atomicAdd(&deg[j], 1);   if (m < MAXDEG) cols[(size_t)j * MAXDEG + m] = row;
        }
        if (v.z != 0.f && jb + 2 > row) {
            int j = jb + 2;
            int p = atomicAdd(&deg[row], 1); if (p < MAXDEG) cols[(size_t)row * MAXDEG + p] = j;
            int m = atomicAdd(&deg[j], 1);   if (m < MAXDEG) cols[(size_t)j * MAXDEG + m] = row;
        }
        if (v.w != 0.f && jb + 3 > row) {
            int j = jb + 3;
            int p = atomicAdd(&deg[row], 1); if (p < MAXDEG) cols[(size_t)row * MAXDEG + p] = j;
            int m = atomicAdd(&deg[j], 1);   if (m < MAXDEG) cols[(size_t)j * MAXDEG + m] = row;
        }
    }
}

// ---------------------------------------------------------------------------
// MFMA GEMM (bf16x3): enc (EPI=0: relu(+bias), also emits bf16-hi X) and
// dec (EPI=2: +bias, col guard). r6-verified core.
// ---------------------------------------------------------------------------
template <int K, int NTOT, int NT, int EPI>
__global__ __launch_bounds__(256) void mfma_gemm(const unsigned short* __restrict__ Ah,
                                                 const unsigned short* __restrict__ Al,
                                                 const unsigned short* __restrict__ Ph,
                                                 const unsigned short* __restrict__ Pl,
                                                 const float* __restrict__ aux,
                                                 float* __restrict__ out,
                                                 unsigned short* __restrict__ oh) {
    int tid = threadIdx.x;
    int wave = tid >> 6, lane = tid & 63;
    int rowA = blockIdx.x * 64 + wave * 16 + (lane & 15);
    if (rowA >= NN) rowA = NN - 1;
    int ct0 = blockIdx.y * NT;
    int koff = (lane >> 4) << 3;

    floatx4 acc[NT];
#pragma unroll
    for (int t = 0; t < NT; ++t) acc[t] = (floatx4){0.f, 0.f, 0.f, 0.f};

#pragma unroll
    for (int ks = 0; ks < K / 32; ++ks) {
        short8v a_h = *(const short8v*)(Ah + (size_t)rowA * K + ks * 32 + koff);
        short8v a_l = *(const short8v*)(Al + (size_t)rowA * K + ks * 32 + koff);
        const unsigned short* bph = Ph + ((size_t)(ks * NTOT + ct0) * 64 + lane) * 8;
        const unsigned short* bpl = Pl + ((size_t)(ks * NTOT + ct0) * 64 + lane) * 8;
#pragma unroll
        for (int t = 0; t < NT; ++t) {
            short8v b_h = *(const short8v*)(bph + t * 512);
            short8v b_l = *(const short8v*)(bpl + t * 512);
            acc[t] = __builtin_amdgcn_mfma_f32_16x16x32_bf16(a_h, b_h, acc[t], 0, 0, 0);
            acc[t] = __builtin_amdgcn_mfma_f32_16x16x32_bf16(a_l, b_h, acc[t], 0, 0, 0);
            acc[t] = __builtin_amdgcn_mfma_f32_16x16x32_bf16(a_h, b_l, acc[t], 0, 0, 0);
        }
    }

    int rbase = blockIdx.x * 64 + wave * 16 + ((lane >> 4) << 2);
    int cbase = ct0 * 16 + (lane & 15);
#pragma unroll
    for (int t = 0; t < NT; ++t) {
        int c = cbase + t * 16;
#pragma unroll
        for (int i = 0; i < 4; ++i) {
            int r = rbase + i;
            if (r < NN) {
                float v = acc[t][i];
                if (EPI == 0) {
                    float o = fmaxf(v + aux[c], 0.f);
                    out[(size_t)r * NHID + c] = o;
                    oh[(size_t)r * NHID + c] = bf16_rne(o);
                } else {
                    if (c < NCLASS) out[(size_t)r * NCLASS + c] = v + aux[c];
                }
            }
        }
    }
}

// ---------------------------------------------------------------------------
// layer_body: shared implementation for layer_fused and probe_layer.
// 16 rows/block, 4 waves. Gather = depth-2 software pipeline: prefetch row
// j+1 (address via __shfl from prefetched c_pre) while fma-ing row j;
// 4 interleaved rows/wave -> 8 loads in flight/wave. Neighbors from bf16-hi
// XH (5 MB working set); self term f32. Phase 2: bf16x3 MFMA from
// XOR-swizzled LDS Y tile. Epilogue: Xn = Xc + relu(Xc+acc), emits bf16-hi;
// wsplit adds lo residual for the decoder.
// ---------------------------------------------------------------------------
static __device__ __forceinline__ void layer_body(const int* __restrict__ cols,
                                                  const int* __restrict__ deg,
                                                  const float* __restrict__ Xc,
                                                  const unsigned short* __restrict__ XH,
                                                  const unsigned short* __restrict__ PWh,
                                                  const unsigned short* __restrict__ PWl,
                                                  float* __restrict__ Xn,
                                                  unsigned short* __restrict__ oh,
                                                  unsigned short* __restrict__ ol,
                                                  int wsplit, int bx) {
    __shared__ float4 Ylds[16][64];                 // 16 KB
    int tid = threadIdx.x, wave = tid >> 6, lane = tid & 63;
    const float4* Xv = (const float4*)Xc;
    const ushort4* XHv = (const ushort4*)XH;

    // ---- phase 1: depth-2 pipelined gather of 4 interleaved rows ----
    int   dcl[4];
    float di[4];
    int   c_pre[4];
    float w_pre[4];
    float4 acc[4];
#pragma unroll
    for (int rr = 0; rr < 4; ++rr) {
        int r = bx * 16 + wave * 4 + rr;            // < NN always (625*16=NN)
        int draw = deg[r];
        di[rr] = rsqrtf((float)(draw + 1));
        dcl[rr] = draw < MAXDEG ? draw : MAXDEG;
        const int* crow = cols + (size_t)r * MAXDEG;
        int cp = (lane < dcl[rr]) ? crow[lane] : r;  // default r: always valid addr
        c_pre[rr] = cp;
        w_pre[rr] = rsqrtf((float)(deg[cp] + 1));
        float4 xs = Xv[(size_t)r * 64 + lane];      // self term in f32
        acc[rr] = make_float4(di[rr] * xs.x, di[rr] * xs.y,
                              di[rr] * xs.z, di[rr] * xs.w);
    }
    int dmax = max(max(dcl[0], dcl[1]), max(dcl[2], dcl[3]));

    ushort4 xq[4];
    float   wq[4];
#pragma unroll
    for (int rr = 0; rr < 4; ++rr) {                // prologue: prefetch j=0
        int c = __shfl(c_pre[rr], 0);
        wq[rr] = __shfl(w_pre[rr], 0);
        xq[rr] = XHv[(size_t)c * 64 + lane];
    }
    for (int j = 0; j < dmax; ++j) {
#pragma unroll
        for (int rr = 0; rr < 4; ++rr) {
            ushort4 xc = xq[rr];                    // consume j
            float   wc = wq[rr];
            int jn = (j + 1) & 63;                  // prefetch j+1 (wrap-safe)
            int c = __shfl(c_pre[rr], jn);
            wq[rr] = __shfl(w_pre[rr], jn);
            xq[rr] = XHv[(size_t)c * 64 + lane];
            if (j < dcl[rr]) {                      // wave-uniform guard
                acc[rr].x = fmaf(wc, bf16_f32(xc.x), acc[rr].x);
                acc[rr].y = fmaf(wc, bf16_f32(xc.y), acc[rr].y);
                acc[rr].z = fmaf(wc, bf16_f32(xc.z), acc[rr].z);
                acc[rr].w = fmaf(wc, bf16_f32(xc.w), acc[rr].w);
            }
        }
    }
#pragma unroll
    for (int rr = 0; rr < 4; ++rr) {
        int lr = wave * 4 + rr;
        float4 o = make_float4(di[rr] * acc[rr].x, di[rr] * acc[rr].y,
                               di[rr] * acc[rr].z, di[rr] * acc[rr].w);
        Ylds[lr][lane ^ (lr & 7)] = o;
    }
    __syncthreads();

    // ---- phase 2: GEMM 16x256 = Y(16x256) * Wm(256x256), bf16x3 ----
    int wc2 = wave;
    floatx4 acc2[4];
#pragma unroll
    for (int t = 0; t < 4; ++t) acc2[t] = (floatx4){0.f, 0.f, 0.f, 0.f};

#pragma unroll
    for (int ks = 0; ks < 8; ++ks) {
        int lr = lane & 15;
        int q = ks * 8 + ((lane >> 4) << 1);
        float4 fa = Ylds[lr][q ^ (lr & 7)];
        float4 fb = Ylds[lr][(q + 1) ^ (lr & 7)];
        float va[8] = {fa.x, fa.y, fa.z, fa.w, fb.x, fb.y, fb.z, fb.w};
        short8v a_h, a_l;
#pragma unroll
        for (int jj = 0; jj < 8; ++jj) {
            unsigned short h = bf16_rne(va[jj]);
            a_h[jj] = (short)h;
            a_l[jj] = (short)bf16_rne(va[jj] - bf16_f32(h));
        }
        const unsigned short* bph = PWh + ((size_t)(ks * 16 + wc2 * 4) * 64 + lane) * 8;
        const unsigned short* bpl = PWl + ((size_t)(ks * 16 + wc2 * 4) * 64 + lane) * 8;
#pragma unroll
        for (int t = 0; t < 4; ++t) {
            short8v b_h = *(const short8v*)(bph + t * 512);
            short8v b_l = *(const short8v*)(bpl + t * 512);
            acc2[t] = __builtin_amdgcn_mfma_f32_16x16x32_bf16(a_h, b_h, acc2[t], 0, 0, 0);
            acc2[t] = __builtin_amdgcn_mfma_f32_16x16x32_bf16(a_l, b_h, acc2[t], 0, 0, 0);
            acc2[t] = __builtin_amdgcn_mfma_f32_16x16x32_bf16(a_h, b_l, acc2[t], 0, 0, 0);
        }
    }

    // ---- epilogue: Xn = Xc + relu(Xc + acc); XHn = bf16(Xn) ----
    int rb = bx * 16 + ((lane >> 4) << 2);
    int cb = wc2 * 64 + (lane & 15);
#pragma unroll
    for (int t = 0; t < 4; ++t) {
        int c = cb + t * 16;
#pragma unroll
        for (int i = 0; i < 4; ++i) {
            int r = rb + i;
            float v = acc2[t][i];
            float xv = Xc[(size_t)r * NHID + c];
            float o = xv + fmaxf(xv + v, 0.f);
            Xn[(size_t)r * NHID + c] = o;
            unsigned short h = bf16_rne(o);
            oh[(size_t)r * NHID + c] = h;
            if (wsplit) {
                ol[(size_t)r * NHID + c] = bf16_rne(o - bf16_f32(h));
            }
        }
    }
    __syncthreads();                                // rep-safety for probe
}

__global__ __launch_bounds__(256) void layer_fused(const int* __restrict__ cols,
                                                   const int* __restrict__ deg,
                                                   const float* __restrict__ Xc,
                                                   const unsigned short* __restrict__ XH,
                                                   const unsigned short* __restrict__ PWh,
                                                   const unsigned short* __restrict__ PWl,
                                                   float* __restrict__ Xn,
                                                   unsigned short* __restrict__ oh,
                                                   unsigned short* __restrict__ ol,
                                                   int wsplit) {
    layer_body(cols, deg, Xc, XH, PWh, PWl, Xn, oh, ol, wsplit, blockIdx.x);
}

// ---------------------------------------------------------------------------
// probe_layer: DIAGNOSTIC. 16 identical reps of layer_body into scratch ->
// one dispatch of ~16L us that surfaces in rocprof top-5 with its own
// counters (MfmaUtil/VALUBusy/hbm/Occupancy). Idempotent (same writes/rep).
// ---------------------------------------------------------------------------
__global__ __launch_bounds__(256) void probe_layer(const int* __restrict__ cols,
                                                   const int* __restrict__ deg,
                                                   const float* __restrict__ Xc,
                                                   const unsigned short* __restrict__ XH,
                                                   const unsigned short* __restrict__ PWh,
                                                   const unsigned short* __restrict__ PWl,
                                                   float* __restrict__ Xs,
                                                   unsigned short* __restrict__ XHs) {
    for (int rep = 0; rep < 16; ++rep) {
        layer_body(cols, deg, Xc, XH, PWh, PWl, Xs, XHs, nullptr, 0, blockIdx.x);
    }
}

// ---------------------------------------------------------------------------
extern "C" void kernel_launch(void* const* d_in, const int* in_sizes, int n_in,
                              void* d_out, int out_size, void* d_ws, size_t ws_size,
                              hipStream_t stream) {
    const float* x      = (const float*)d_in[0];
    const float* A      = (const float*)d_in[1];
    const float* enc_w  = (const float*)d_in[2];
    const float* enc_b  = (const float*)d_in[3];
    const float* conv_w = (const float*)d_in[4];
    const float* dec_w  = (const float*)d_in[5];
    const float* dec_b  = (const float*)d_in[6];
    float* out = (float*)d_out;

    char* w = (char*)d_ws;
    auto alloc = [&](size_t bytes) {
        char* p = w;
        w += (bytes + 255) & ~(size_t)255;
        return p;
    };
    int*            cols = (int*)alloc((size_t)NN * MAXDEG * 4);
    int*            deg  = (int*)alloc((size_t)NN * 4);
    unsigned short* xh   = (unsigned short*)alloc((size_t)NN * NFEAT * 2);
    unsigned short* xl   = (unsigned short*)alloc((size_t)NN * NFEAT * 2);
    unsigned short* PEh  = (unsigned short*)alloc((size_t)NFEAT * NHID * 2);
    unsigned short* PEl  = (unsigned short*)alloc((size_t)NFEAT * NHID * 2);
    unsigned short* PWh  = (unsigned short*)alloc((size_t)NHID * NHID * 2);
    unsigned short* PWl  = (unsigned short*)alloc((size_t)NHID * NHID * 2);
    unsigned short* PDh  = (unsigned short*)alloc((size_t)NHID * 48 * 2);
    unsigned short* PDl  = (unsigned short*)alloc((size_t)NHID * 48 * 2);
    float*          Xa   = (float*)alloc((size_t)NN * NHID * 4);
    float*          Xb   = (float*)alloc((size_t)NN * NHID * 4);
    unsigned short* XHa  = (unsigned short*)alloc((size_t)NN * NHID * 2);
    unsigned short* XHb  = (unsigned short*)alloc((size_t)NN * NHID * 2);
    unsigned short* Xfl  = (unsigned short*)alloc((size_t)NN * NHID * 2);
    float*          Xs   = (float*)alloc((size_t)NN * NHID * 4);   // probe scratch
    unsigned short* XHs  = (unsigned short*)alloc((size_t)NN * NHID * 2);

    prep<<<5856, 256, 0, stream>>>(enc_w, conv_w, dec_w, x,
                                   PEh, PEl, PWh, PWl, PDh, PDl, xh, xl, deg);
    scan_upper<<<(NN + 3) / 4, 256, 0, stream>>>(A, cols, deg);

    dim3 g4((NN + 63) / 64, 4);
    mfma_gemm<NFEAT, 16, 4, 0><<<g4, 256, 0, stream>>>(xh, xl, PEh, PEl, enc_b,
                                                       Xa, XHa);

    // diagnostic probe (removed next round): 16x layer into scratch
    probe_layer<<<NN / 16, 256, 0, stream>>>(cols, deg, Xa, XHa, PWh, PWl, Xs, XHs);

    float* Xcur = Xa;           unsigned short* XHcur = XHa;
    float* Xnxt = Xb;           unsigned short* XHnxt = XHb;
    for (int layer = 0; layer < 4; ++layer) {
        layer_fused<<<NN / 16, 256, 0, stream>>>(cols, deg, Xcur, XHcur, PWh, PWl,
                                                 Xnxt, XHnxt, Xfl,
                                                 layer == 3 ? 1 : 0);
        float* t = Xcur; Xcur = Xnxt; Xnxt = t;
        unsigned short* th = XHcur; XHcur = XHnxt; XHnxt = th;
    }
    dim3 g1((NN + 63) / 64, 1);
    mfma_gemm<NHID, 3, 3, 2><<<g1, 256, 0, stream>>>(XHcur, Xfl, PDh, PDl, dec_b,
                                                     out, nullptr);
}

// Round 13
// 717.037 us; speedup vs baseline: 1.5869x; 1.5869x over previous
//
#include <hip/hip_runtime.h>
#include <math.h>

#define NN 10000
#define NFEAT 512
#define NHID 256
#define NCLASS 40
#define MAXDEG 64

typedef __attribute__((ext_vector_type(8))) short short8v;            // 8 bf16
typedef __attribute__((ext_vector_type(8))) unsigned short ushort8v;  // 8 bf16 bits
typedef __attribute__((ext_vector_type(4))) float floatx4;            // MFMA acc

static __device__ __forceinline__ unsigned short bf16_rne(float f) {
    unsigned u = __builtin_bit_cast(unsigned, f);
    u += 0x7fffu + ((u >> 16) & 1u);
    return (unsigned short)(u >> 16);
}
static __device__ __forceinline__ float bf16_f32(unsigned short h) {
    unsigned u = ((unsigned)h) << 16;
    return __builtin_bit_cast(float, u);
}

// ---------------------------------------------------------------------------
// prep: fused one-shot setup (packs + x split + deg zero). Layout:
//   P[((ks*NTOT+ct)*64+lane)*8+j] = B[k][c],
//   k = ks*32 + 8*(lane>>4) + j,  c = ct*16 + (lane&15)
// ---------------------------------------------------------------------------
__global__ __launch_bounds__(256) void prep(const float* __restrict__ EW,
                                            const float* __restrict__ W,
                                            const float* __restrict__ DW,
                                            const float* __restrict__ x,
                                            unsigned short* __restrict__ PEh,
                                            unsigned short* __restrict__ PEl,
                                            unsigned short* __restrict__ PWh,
                                            unsigned short* __restrict__ PWl,
                                            unsigned short* __restrict__ PDh,
                                            unsigned short* __restrict__ PDl,
                                            unsigned short* __restrict__ xh,
                                            unsigned short* __restrict__ xl,
                                            int* __restrict__ deg) {
    int b = blockIdx.x;
    if (b < 512) {                                  // enc pack
        int idx = b * 256 + threadIdx.x;
        int j = idx & 7, lane = (idx >> 3) & 63;
        int ctks = idx >> 9;
        int ct = ctks & 15, ks = ctks >> 4;
        int k = ks * 32 + ((lane >> 4) << 3) + j;
        int c = ct * 16 + (lane & 15);
        float w = EW[(size_t)c * NFEAT + k];
        unsigned short h = bf16_rne(w);
        PEh[idx] = h;
        PEl[idx] = bf16_rne(w - bf16_f32(h));
    } else if (b < 768) {                           // layer pack (0.25*(W+W^T))
        int idx = (b - 512) * 256 + threadIdx.x;
        int j = idx & 7, lane = (idx >> 3) & 63;
        int ctks = idx >> 9;
        int ct = ctks & 15, ks = ctks >> 4;
        int k = ks * 32 + ((lane >> 4) << 3) + j;
        int c = ct * 16 + (lane & 15);
        float w = 0.25f * (W[k * NHID + c] + W[c * NHID + k]);
        unsigned short h = bf16_rne(w);
        PWh[idx] = h;
        PWl[idx] = bf16_rne(w - bf16_f32(h));
    } else if (b < 816) {                           // dec pack
        int idx = (b - 768) * 256 + threadIdx.x;    // 12288
        int j = idx & 7, lane = (idx >> 3) & 63;
        int ctks = idx >> 9;
        int ct = ctks % 3, ks = ctks / 3;
        int k = ks * 32 + ((lane >> 4) << 3) + j;
        int c = ct * 16 + (lane & 15);
        float w = (c < NCLASS) ? DW[(size_t)c * NHID + k] : 0.f;
        unsigned short h = bf16_rne(w);
        PDh[idx] = h;
        PDl[idx] = bf16_rne(w - bf16_f32(h));
    } else if (b < 5816) {                          // split x (f32 -> bf16 hi/lo)
        int i = (b - 816) * 256 + threadIdx.x;      // 1,280,000 float4
        float4 v = ((const float4*)x)[i];
        ushort4 h, l;
        h.x = bf16_rne(v.x); l.x = bf16_rne(v.x - bf16_f32(h.x));
        h.y = bf16_rne(v.y); l.y = bf16_rne(v.y - bf16_f32(h.y));
        h.z = bf16_rne(v.z); l.z = bf16_rne(v.z - bf16_f32(h.z));
        h.w = bf16_rne(v.w); l.w = bf16_rne(v.w - bf16_f32(h.w));
        ((ushort4*)xh)[i] = h;
        ((ushort4*)xl)[i] = l;
    } else {                                        // zero deg
        int i = (b - 5816) * 256 + threadIdx.x;
        if (i < NN) deg[i] = 0;
    }
}

// ---------------------------------------------------------------------------
// scan_upper: symmetric A -> scan j > i only (200 MB), mirror edges via
// atomic index reservation.
// ---------------------------------------------------------------------------
__global__ __launch_bounds__(256) void scan_upper(const float* __restrict__ A,
                                                  int* __restrict__ cols,
                                                  int* __restrict__ deg) {
    int wave = threadIdx.x >> 6;
    int lane = threadIdx.x & 63;
    int row = blockIdx.x * 4 + wave;
    if (row >= NN) return;
    const float4* Arow = (const float4*)(A + (size_t)row * NN);
    int qstart = (row + 1) >> 2;
    for (int q = qstart + lane; q < NN / 4; q += 64) {
        float4 v = Arow[q];
        int jb = 4 * q;
        if (v.x != 0.f && jb + 0 > row) {
            int p = atomicAdd(&deg[row], 1); if (p < MAXDEG) cols[(size_t)row * MAXDEG + p] = jb;
            int m = atomicAdd(&deg[jb], 1);  if (m < MAXDEG) cols[(size_t)jb * MAXDEG + m] = row;
        }
        if (v.y != 0.f && jb + 1 > row) {
            int j = jb + 1;
            int p = atomicAdd(&deg[row], 1); if (p < MAXDEG) cols[(size_t)row * MAXDEG + p] = j;
            int m = atomicAdd(&deg[j], 1);   if (m < MAXDEG) cols[(size_t)j * MAXDEG + m] = row;
        }
        if (v.z != 0.f && jb + 2 > row) {
            int j = jb + 2;
            int p = atomicAdd(&deg[row], 1); if (p < MAXDEG) cols[(size_t)row * MAXDEG + p] = j;
            int m = atomicAdd(&deg[j], 1);   if (m < MAXDEG) cols[(size_t)j * MAXDEG + m] = row;
        }
        if (v.w != 0.f && jb + 3 > row) {
            int j = jb + 3;
            int p = atomicAdd(&deg[row], 1); if (p < MAXDEG) cols[(size_t)row * MAXDEG + p] = j;
            int m = atomicAdd(&deg[j], 1);   if (m < MAXDEG) cols[(size_t)j * MAXDEG + m] = row;
        }
    }
}

// finalize: dinv from full degree; clamp stored deg for the gather loop.
__global__ __launch_bounds__(256) void finalize(int* __restrict__ deg,
                                                float* __restrict__ dinv) {
    int i = blockIdx.x * 256 + threadIdx.x;
    if (i >= NN) return;
    int d = deg[i];
    dinv[i] = rsqrtf((float)(d + 1));
    deg[i] = d < MAXDEG ? d : MAXDEG;
}

// ---------------------------------------------------------------------------
// MFMA GEMM (bf16x3): enc (EPI=0: relu(+bias), also emits bf16-hi X) and
// dec (EPI=2: +bias, col guard). r6-verified core.
// ---------------------------------------------------------------------------
template <int K, int NTOT, int NT, int EPI>
__global__ __launch_bounds__(256) void mfma_gemm(const unsigned short* __restrict__ Ah,
                                                 const unsigned short* __restrict__ Al,
                                                 const unsigned short* __restrict__ Ph,
                                                 const unsigned short* __restrict__ Pl,
                                                 const float* __restrict__ aux,
                                                 float* __restrict__ out,
                                                 unsigned short* __restrict__ oh) {
    int tid = threadIdx.x;
    int wave = tid >> 6, lane = tid & 63;
    int rowA = blockIdx.x * 64 + wave * 16 + (lane & 15);
    if (rowA >= NN) rowA = NN - 1;
    int ct0 = blockIdx.y * NT;
    int koff = (lane >> 4) << 3;

    floatx4 acc[NT];
#pragma unroll
    for (int t = 0; t < NT; ++t) acc[t] = (floatx4){0.f, 0.f, 0.f, 0.f};

#pragma unroll
    for (int ks = 0; ks < K / 32; ++ks) {
        short8v a_h = *(const short8v*)(Ah + (size_t)rowA * K + ks * 32 + koff);
        short8v a_l = *(const short8v*)(Al + (size_t)rowA * K + ks * 32 + koff);
        const unsigned short* bph = Ph + ((size_t)(ks * NTOT + ct0) * 64 + lane) * 8;
        const unsigned short* bpl = Pl + ((size_t)(ks * NTOT + ct0) * 64 + lane) * 8;
#pragma unroll
        for (int t = 0; t < NT; ++t) {
            short8v b_h = *(const short8v*)(bph + t * 512);
            short8v b_l = *(const short8v*)(bpl + t * 512);
            acc[t] = __builtin_amdgcn_mfma_f32_16x16x32_bf16(a_h, b_h, acc[t], 0, 0, 0);
            acc[t] = __builtin_amdgcn_mfma_f32_16x16x32_bf16(a_l, b_h, acc[t], 0, 0, 0);
            acc[t] = __builtin_amdgcn_mfma_f32_16x16x32_bf16(a_h, b_l, acc[t], 0, 0, 0);
        }
    }

    int rbase = blockIdx.x * 64 + wave * 16 + ((lane >> 4) << 2);
    int cbase = ct0 * 16 + (lane & 15);
#pragma unroll
    for (int t = 0; t < NT; ++t) {
        int c = cbase + t * 16;
#pragma unroll
        for (int i = 0; i < 4; ++i) {
            int r = rbase + i;
            if (r < NN) {
                float v = acc[t][i];
                if (EPI == 0) {
                    float o = fmaxf(v + aux[c], 0.f);
                    out[(size_t)r * NHID + c] = o;
                    oh[(size_t)r * NHID + c] = bf16_rne(o);
                } else {
                    if (c < NCLASS) out[(size_t)r * NCLASS + c] = v + aux[c];
                }
            }
        }
    }
}

// ---------------------------------------------------------------------------
// layer_fused v4: 16 rows/block, 256 threads (4 waves), 625 blocks.
// Gather (latency-bound per r12 probe: MfmaUtil 5%, VALU 21%, hbm 6%, occ 9%):
//  - pair-parallel halves: lanes [0,32) process neighbor 2p, lanes [32,64)
//    neighbor 2p+1; each lane loads 16B (ushort8 of bf16 XH) -> iterations
//    halved, in-flight doubled vs v3.
//  - depth-3/4 pipeline: two pending issue states (A=p+2, B=p+3), statically
//    unrolled (no runtime-indexed reg arrays).
//  - wave-uniform scalar indexing: crow[j]/dinv[c] are uniform loads (s_load
//    path), no per-neighbor __shfl in the issue stream.
//  - cross-half reduce: one __shfl_xor(.,32) pass, then half 0 writes LDS.
// LDS layout: slot s<32 = feats s*8+0..3, slot s+32 = feats s*8+4..7 (XOR
// swizzled by row&7). Phase 2 reads (s, s+32) accordingly; fragment values
// identical to v3. Epilogue unchanged.
// ---------------------------------------------------------------------------
__global__ __launch_bounds__(256) void layer_fused(const int* __restrict__ cols,
                                                   const int* __restrict__ deg,
                                                   const float* __restrict__ dinv,
                                                   const float* __restrict__ Xc,
                                                   const unsigned short* __restrict__ XH,
                                                   const unsigned short* __restrict__ PWh,
                                                   const unsigned short* __restrict__ PWl,
                                                   float* __restrict__ Xn,
                                                   unsigned short* __restrict__ oh,
                                                   unsigned short* __restrict__ ol,
                                                   int wsplit) {
    __shared__ float4 Ylds[16][64];                 // 16 KB
    int tid = threadIdx.x, wave = tid >> 6, lane = tid & 63;
    int lane32 = lane & 31, half = lane >> 5;
    int bx = blockIdx.x;
    const ushort8v* XH8 = (const ushort8v*)XH;      // row = 32 ushort8

    // ---- phase 1 state ----
    int   dcl[4];
    float di[4];
    const int* crowp[4];
    float accv[4][8];
#pragma unroll
    for (int rr = 0; rr < 4; ++rr) {
        int r = bx * 16 + wave * 4 + rr;            // < NN always (625*16=NN)
        dcl[rr] = deg[r];                           // pre-clamped <= 64
        di[rr]  = dinv[r];
        crowp[rr] = cols + (size_t)r * MAXDEG;
        if (half == 0) {                            // self term (f32), half 0 only
            const float4* xr = (const float4*)(Xc + (size_t)r * NHID);
            float4 s0 = xr[lane32 * 2], s1 = xr[lane32 * 2 + 1];
            float w = di[rr];
            accv[rr][0] = w * s0.x; accv[rr][1] = w * s0.y;
            accv[rr][2] = w * s0.z; accv[rr][3] = w * s0.w;
            accv[rr][4] = w * s1.x; accv[rr][5] = w * s1.y;
            accv[rr][6] = w * s1.z; accv[rr][7] = w * s1.w;
        } else {
#pragma unroll
            for (int k = 0; k < 8; ++k) accv[rr][k] = 0.f;
        }
    }
    int dmax = max(max(dcl[0], dcl[1]), max(dcl[2], dcl[3]));
    int npairs = (dmax + 1) >> 1;

    // ---- pipelined gather: states A (even p) and B (odd p) ----
    ushort8v xqA[4], xqB[4];
    float    wqA[4], wqB[4];

#define ISSUE(XQ, WQ, P)                                                     \
    {                                                                        \
        int p_ = (P);                                                        \
        _Pragma("unroll")                                                    \
        for (int rr = 0; rr < 4; ++rr) {                                     \
            int d_ = dcl[rr];                                                \
            int j0 = 2 * p_, j1 = j0 + 1;                                    \
            int c0 = crowp[rr][j0 < 63 ? j0 : 63];                           \
            int c1 = crowp[rr][j1 < 63 ? j1 : 63];                           \
            c0 = (j0 < d_) ? c0 : 0;                                         \
            c1 = (j1 < d_) ? c1 : 0;                                         \
            float w0 = (j0 < d_) ? dinv[c0] : 0.f;                           \
            float w1 = (j1 < d_) ? dinv[c1] : 0.f;                           \
            int   c_ = half ? c1 : c0;                                       \
            WQ[rr]   = half ? w1 : w0;                                       \
            XQ[rr]   = XH8[(size_t)c_ * 32 + lane32];                        \
        }                                                                    \
    }

#define CONSUME(XQ, WQ)                                                      \
    {                                                                        \
        _Pragma("unroll")                                                    \
        for (int rr = 0; rr < 4; ++rr) {                                     \
            float w_ = WQ[rr];                                               \
            ushort8v x_ = XQ[rr];                                            \
            _Pragma("unroll")                                                \
            for (int k = 0; k < 8; ++k)                                      \
                accv[rr][k] = fmaf(w_, bf16_f32((unsigned short)x_[k]),      \
                                   accv[rr][k]);                             \
        }                                                                    \
    }

    ISSUE(xqA, wqA, 0)
    ISSUE(xqB, wqB, 1)
    for (int p = 0; p < npairs; p += 2) {
        CONSUME(xqA, wqA)
        ISSUE(xqA, wqA, p + 2)
        CONSUME(xqB, wqB)
        ISSUE(xqB, wqB, p + 3)
    }
#undef ISSUE
#undef CONSUME

    // ---- cross-half reduce + LDS write (half 0) ----
#pragma unroll
    for (int rr = 0; rr < 4; ++rr) {
        int lr = wave * 4 + rr;
        float w = di[rr];
        float s[8];
#pragma unroll
        for (int k = 0; k < 8; ++k)
            s[k] = accv[rr][k] + __shfl_xor(accv[rr][k], 32);
        if (half == 0) {
            float4 o0 = make_float4(w * s[0], w * s[1], w * s[2], w * s[3]);
            float4 o1 = make_float4(w * s[4], w * s[5], w * s[6], w * s[7]);
            Ylds[lr][lane32 ^ (lr & 7)] = o0;
            Ylds[lr][(lane32 + 32) ^ (lr & 7)] = o1;
        }
    }
    __syncthreads();

    // ---- phase 2: GEMM 16x256 = Y(16x256) * Wm(256x256), bf16x3 ----
    int wc2 = wave;
    floatx4 acc2[4];
#pragma unroll
    for (int t = 0; t < 4; ++t) acc2[t] = (floatx4){0.f, 0.f, 0.f, 0.f};

#pragma unroll
    for (int ks = 0; ks < 8; ++ks) {
        int lr = lane & 15;
        int s = ks * 4 + (lane >> 4);               // feats s*8 .. s*8+7
        float4 fa = Ylds[lr][s ^ (lr & 7)];
        float4 fb = Ylds[lr][(s + 32) ^ (lr & 7)];
        float va[8] = {fa.x, fa.y, fa.z, fa.w, fb.x, fb.y, fb.z, fb.w};
        short8v a_h, a_l;
#pragma unroll
        for (int jj = 0; jj < 8; ++jj) {
            unsigned short h = bf16_rne(va[jj]);
            a_h[jj] = (short)h;
            a_l[jj] = (short)bf16_rne(va[jj] - bf16_f32(h));
        }
        const unsigned short* bph = PWh + ((size_t)(ks * 16 + wc2 * 4) * 64 + lane) * 8;
        const unsigned short* bpl = PWl + ((size_t)(ks * 16 + wc2 * 4) * 64 + lane) * 8;
#pragma unroll
        for (int t = 0; t < 4; ++t) {
            short8v b_h = *(const short8v*)(bph + t * 512);
            short8v b_l = *(const short8v*)(bpl + t * 512);
            acc2[t] = __builtin_amdgcn_mfma_f32_16x16x32_bf16(a_h, b_h, acc2[t], 0, 0, 0);
            acc2[t] = __builtin_amdgcn_mfma_f32_16x16x32_bf16(a_l, b_h, acc2[t], 0, 0, 0);
            acc2[t] = __builtin_amdgcn_mfma_f32_16x16x32_bf16(a_h, b_l, acc2[t], 0, 0, 0);
        }
    }

    // ---- epilogue: Xn = Xc + relu(Xc + acc); XHn = bf16(Xn) ----
    int rb = bx * 16 + ((lane >> 4) << 2);
    int cb = wc2 * 64 + (lane & 15);
#pragma unroll
    for (int t = 0; t < 4; ++t) {
        int c = cb + t * 16;
#pragma unroll
        for (int i = 0; i < 4; ++i) {
            int r = rb + i;
            float v = acc2[t][i];
            float xv = Xc[(size_t)r * NHID + c];
            float o = xv + fmaxf(xv + v, 0.f);
            Xn[(size_t)r * NHID + c] = o;
            unsigned short h = bf16_rne(o);
            oh[(size_t)r * NHID + c] = h;
            if (wsplit) {
                ol[(size_t)r * NHID + c] = bf16_rne(o - bf16_f32(h));
            }
        }
    }
}

// ---------------------------------------------------------------------------
extern "C" void kernel_launch(void* const* d_in, const int* in_sizes, int n_in,
                              void* d_out, int out_size, void* d_ws, size_t ws_size,
                              hipStream_t stream) {
    const float* x      = (const float*)d_in[0];
    const float* A      = (const float*)d_in[1];
    const float* enc_w  = (const float*)d_in[2];
    const float* enc_b  = (const float*)d_in[3];
    const float* conv_w = (const float*)d_in[4];
    const float* dec_w  = (const float*)d_in[5];
    const float* dec_b  = (const float*)d_in[6];
    float* out = (float*)d_out;

    char* w = (char*)d_ws;
    auto alloc = [&](size_t bytes) {
        char* p = w;
        w += (bytes + 255) & ~(size_t)255;
        return p;
    };
    int*            cols = (int*)alloc((size_t)NN * MAXDEG * 4);
    int*            deg  = (int*)alloc((size_t)NN * 4);
    float*          dinv = (float*)alloc((size_t)NN * 4);
    unsigned short* xh   = (unsigned short*)alloc((size_t)NN * NFEAT * 2);
    unsigned short* xl   = (unsigned short*)alloc((size_t)NN * NFEAT * 2);
    unsigned short* PEh  = (unsigned short*)alloc((size_t)NFEAT * NHID * 2);
    unsigned short* PEl  = (unsigned short*)alloc((size_t)NFEAT * NHID * 2);
    unsigned short* PWh  = (unsigned short*)alloc((size_t)NHID * NHID * 2);
    unsigned short* PWl  = (unsigned short*)alloc((size_t)NHID * NHID * 2);
    unsigned short* PDh  = (unsigned short*)alloc((size_t)NHID * 48 * 2);
    unsigned short* PDl  = (unsigned short*)alloc((size_t)NHID * 48 * 2);
    float*          Xa   = (float*)alloc((size_t)NN * NHID * 4);
    float*          Xb   = (float*)alloc((size_t)NN * NHID * 4);
    unsigned short* XHa  = (unsigned short*)alloc((size_t)NN * NHID * 2);
    unsigned short* XHb  = (unsigned short*)alloc((size_t)NN * NHID * 2);
    unsigned short* Xfl  = (unsigned short*)alloc((size_t)NN * NHID * 2);

    prep<<<5856, 256, 0, stream>>>(enc_w, conv_w, dec_w, x,
                                   PEh, PEl, PWh, PWl, PDh, PDl, xh, xl, deg);
    scan_upper<<<(NN + 3) / 4, 256, 0, stream>>>(A, cols, deg);
    finalize<<<(NN + 255) / 256, 256, 0, stream>>>(deg, dinv);

    dim3 g4((NN + 63) / 64, 4);
    mfma_gemm<NFEAT, 16, 4, 0><<<g4, 256, 0, stream>>>(xh, xl, PEh, PEl, enc_b,
                                                       Xa, XHa);

    float* Xcur = Xa;           unsigned short* XHcur = XHa;
    float* Xnxt = Xb;           unsigned short* XHnxt = XHb;
    for (int layer = 0; layer < 4; ++layer) {
        layer_fused<<<NN / 16, 256, 0, stream>>>(cols, deg, dinv, Xcur, XHcur,
                                                 PWh, PWl, Xnxt, XHnxt, Xfl,
                                                 layer == 3 ? 1 : 0);
        float* t = Xcur; Xcur = Xnxt; Xnxt = t;
        unsigned short* th = XHcur; XHcur = XHnxt; XHnxt = th;
    }
    dim3 g1((NN + 63) / 64, 1);
    mfma_gemm<NHID, 3, 3, 2><<<g1, 256, 0, stream>>>(XHcur, Xfl, PDh, PDl, dec_b,
                                                     out, nullptr);
}

// Round 14
// 664.648 us; speedup vs baseline: 1.7120x; 1.0788x over previous
//
#include <hip/hip_runtime.h>
#include <math.h>

#define NN 10000
#define NFEAT 512
#define NHID 256
#define NCLASS 40
#define MAXDEG 64

typedef __attribute__((ext_vector_type(8))) short short8v;   // 8 bf16 (4 VGPR)
typedef __attribute__((ext_vector_type(4))) float floatx4;   // MFMA acc

static __device__ __forceinline__ unsigned short bf16_rne(float f) {
    unsigned u = __builtin_bit_cast(unsigned, f);
    u += 0x7fffu + ((u >> 16) & 1u);
    return (unsigned short)(u >> 16);
}
static __device__ __forceinline__ float bf16_f32(unsigned short h) {
    unsigned u = ((unsigned)h) << 16;
    return __builtin_bit_cast(float, u);
}

// ---------------------------------------------------------------------------
// prep: fused one-shot setup (packs + x split + deg zero). Layout:
//   P[((ks*NTOT+ct)*64+lane)*8+j] = B[k][c],
//   k = ks*32 + 8*(lane>>4) + j,  c = ct*16 + (lane&15)
// ---------------------------------------------------------------------------
__global__ __launch_bounds__(256) void prep(const float* __restrict__ EW,
                                            const float* __restrict__ W,
                                            const float* __restrict__ DW,
                                            const float* __restrict__ x,
                                            unsigned short* __restrict__ PEh,
                                            unsigned short* __restrict__ PEl,
                                            unsigned short* __restrict__ PWh,
                                            unsigned short* __restrict__ PWl,
                                            unsigned short* __restrict__ PDh,
                                            unsigned short* __restrict__ PDl,
                                            unsigned short* __restrict__ xh,
                                            unsigned short* __restrict__ xl,
                                            int* __restrict__ deg) {
    int b = blockIdx.x;
    if (b < 512) {                                  // enc pack
        int idx = b * 256 + threadIdx.x;
        int j = idx & 7, lane = (idx >> 3) & 63;
        int ctks = idx >> 9;
        int ct = ctks & 15, ks = ctks >> 4;
        int k = ks * 32 + ((lane >> 4) << 3) + j;
        int c = ct * 16 + (lane & 15);
        float w = EW[(size_t)c * NFEAT + k];
        unsigned short h = bf16_rne(w);
        PEh[idx] = h;
        PEl[idx] = bf16_rne(w - bf16_f32(h));
    } else if (b < 768) {                           // layer pack (0.25*(W+W^T))
        int idx = (b - 512) * 256 + threadIdx.x;
        int j = idx & 7, lane = (idx >> 3) & 63;
        int ctks = idx >> 9;
        int ct = ctks & 15, ks = ctks >> 4;
        int k = ks * 32 + ((lane >> 4) << 3) + j;
        int c = ct * 16 + (lane & 15);
        float w = 0.25f * (W[k * NHID + c] + W[c * NHID + k]);
        unsigned short h = bf16_rne(w);
        PWh[idx] = h;
        PWl[idx] = bf16_rne(w - bf16_f32(h));
    } else if (b < 816) {                           // dec pack (48 cols, NTOT=3)
        int idx = (b - 768) * 256 + threadIdx.x;    // 12288
        int j = idx & 7, lane = (idx >> 3) & 63;
        int ctks = idx >> 9;
        int ct = ctks % 3, ks = ctks / 3;
        int k = ks * 32 + ((lane >> 4) << 3) + j;
        int c = ct * 16 + (lane & 15);
        float w = (c < NCLASS) ? DW[(size_t)c * NHID + k] : 0.f;
        unsigned short h = bf16_rne(w);
        PDh[idx] = h;
        PDl[idx] = bf16_rne(w - bf16_f32(h));
    } else if (b < 5816) {                          // split x (f32 -> bf16 hi/lo)
        int i = (b - 816) * 256 + threadIdx.x;      // 1,280,000 float4
        float4 v = ((const float4*)x)[i];
        ushort4 h, l;
        h.x = bf16_rne(v.x); l.x = bf16_rne(v.x - bf16_f32(h.x));
        h.y = bf16_rne(v.y); l.y = bf16_rne(v.y - bf16_f32(h.y));
        h.z = bf16_rne(v.z); l.z = bf16_rne(v.z - bf16_f32(h.z));
        h.w = bf16_rne(v.w); l.w = bf16_rne(v.w - bf16_f32(h.w));
        ((ushort4*)xh)[i] = h;
        ((ushort4*)xl)[i] = l;
    } else {                                        // zero deg
        int i = (b - 5816) * 256 + threadIdx.x;
        if (i < NN) deg[i] = 0;
    }
}

// ---------------------------------------------------------------------------
// scan_upper: symmetric A -> scan j > i only (200 MB), mirror edges via
// atomic index reservation.
// ---------------------------------------------------------------------------
__global__ __launch_bounds__(256) void scan_upper(const float* __restrict__ A,
                                                  int* __restrict__ cols,
                                                  int* __restrict__ deg) {
    int wave = threadIdx.x >> 6;
    int lane = threadIdx.x & 63;
    int row = blockIdx.x * 4 + wave;
    if (row >= NN) return;
    const float4* Arow = (const float4*)(A + (size_t)row * NN);
    int qstart = (row + 1) >> 2;
    for (int q = qstart + lane; q < NN / 4; q += 64) {
        float4 v = Arow[q];
        int jb = 4 * q;
        if (v.x != 0.f && jb + 0 > row) {
            int p = atomicAdd(&deg[row], 1); if (p < MAXDEG) cols[(size_t)row * MAXDEG + p] = jb;
            int m = atomicAdd(&deg[jb], 1);  if (m < MAXDEG) cols[(size_t)jb * MAXDEG + m] = row;
        }
        if (v.y != 0.f && jb + 1 > row) {
            int j = jb + 1;
            int p = atomicAdd(&deg[row], 1); if (p < MAXDEG) cols[(size_t)row * MAXDEG + p] = j;
            int m = atomicAdd(&deg[j], 1);   if (m < MAXDEG) cols[(size_t)j * MAXDEG + m] = row;
        }
        if (v.z != 0.f && jb + 2 > row) {
            int j = jb + 2;
            int p = atomicAdd(&deg[row], 1); if (p < MAXDEG) cols[(size_t)row * MAXDEG + p] = j;
            int m = atomicAdd(&deg[j], 1);   if (m < MAXDEG) cols[(size_t)j * MAXDEG + m] = row;
        }
        if (v.w != 0.f && jb + 3 > row) {
            int j = jb + 3;
            int p = atomicAdd(&deg[row], 1); if (p < MAXDEG) cols[(size_t)row * MAXDEG + p] = j;
            int m = atomicAdd(&deg[j], 1);   if (m < MAXDEG) cols[(size_t)j * MAXDEG + m] = row;
        }
    }
}

// ---------------------------------------------------------------------------
// enc_fin: blocks [0,628) = encoder MFMA GEMM (bx=b%157, by=b/157, NT=4);
//          blocks [628,668) = finalize (dinv from raw deg; clamp deg).
// Enc: X = relu(x @ enc_w^T + b), emits f32 Xa + bf16-hi XHa.
// ---------------------------------------------------------------------------
__global__ __launch_bounds__(256) void enc_fin(const unsigned short* __restrict__ Ah,
                                               const unsigned short* __restrict__ Al,
                                               const unsigned short* __restrict__ Ph,
                                               const unsigned short* __restrict__ Pl,
                                               const float* __restrict__ bias,
                                               float* __restrict__ outX,
                                               unsigned short* __restrict__ outH,
                                               int* __restrict__ deg,
                                               float* __restrict__ dinv) {
    int b = blockIdx.x;
    if (b >= 628) {                                 // finalize tail
        int i = (b - 628) * 256 + threadIdx.x;
        if (i < NN) {
            int d = deg[i];
            dinv[i] = rsqrtf((float)(d + 1));
            deg[i] = d < MAXDEG ? d : MAXDEG;
        }
        return;
    }
    const int K = NFEAT, NTOT = 16, NT = 4;
    int bx = b % 157, by = b / 157;
    int tid = threadIdx.x;
    int wave = tid >> 6, lane = tid & 63;
    int rowA = bx * 64 + wave * 16 + (lane & 15);
    if (rowA >= NN) rowA = NN - 1;
    int ct0 = by * NT;
    int koff = (lane >> 4) << 3;

    floatx4 acc[NT];
#pragma unroll
    for (int t = 0; t < NT; ++t) acc[t] = (floatx4){0.f, 0.f, 0.f, 0.f};

#pragma unroll
    for (int ks = 0; ks < K / 32; ++ks) {
        short8v a_h = *(const short8v*)(Ah + (size_t)rowA * K + ks * 32 + koff);
        short8v a_l = *(const short8v*)(Al + (size_t)rowA * K + ks * 32 + koff);
        const unsigned short* bph = Ph + ((size_t)(ks * NTOT + ct0) * 64 + lane) * 8;
        const unsigned short* bpl = Pl + ((size_t)(ks * NTOT + ct0) * 64 + lane) * 8;
#pragma unroll
        for (int t = 0; t < NT; ++t) {
            short8v b_h = *(const short8v*)(bph + t * 512);
            short8v b_l = *(const short8v*)(bpl + t * 512);
            acc[t] = __builtin_amdgcn_mfma_f32_16x16x32_bf16(a_h, b_h, acc[t], 0, 0, 0);
            acc[t] = __builtin_amdgcn_mfma_f32_16x16x32_bf16(a_l, b_h, acc[t], 0, 0, 0);
            acc[t] = __builtin_amdgcn_mfma_f32_16x16x32_bf16(a_h, b_l, acc[t], 0, 0, 0);
        }
    }

    int rbase = bx * 64 + wave * 16 + ((lane >> 4) << 2);
    int cbase = ct0 * 16 + (lane & 15);
#pragma unroll
    for (int t = 0; t < NT; ++t) {
        int c = cbase + t * 16;
#pragma unroll
        for (int i = 0; i < 4; ++i) {
            int r = rbase + i;
            if (r < NN) {
                float o = fmaxf(acc[t][i] + bias[c], 0.f);
                outX[(size_t)r * NHID + c] = o;
                outH[(size_t)r * NHID + c] = bf16_rne(o);
            }
        }
    }
}

// ---------------------------------------------------------------------------
// layer_fused (r10-v3 body, best measured): 16 rows/block, 4 waves, 625 blocks.
// Phase 1: interleaved gather of 4 rows/wave; neighbor ids/weights prefetched
//   to lanes, broadcast via __shfl; neighbor rows read from bf16-hi XH
//   (L3 random-gather BW floor ~4.3 TB/s — r12 probe; further ILP is null).
// Phase 2: bf16x3 MFMA from XOR-swizzled LDS Y tile.
// DECF=0 epilogue: Xn = Xc + relu(Xc+acc), emits f32 Xn + bf16-hi oh.
// DECF=1 (last layer): skip global Xn/oh entirely; stage Xf tile in LDS
//   (stride 264) and decode in-block: out = Xf @ dec_w^T + dec_b.
// ---------------------------------------------------------------------------
template <int DECF>
__global__ __launch_bounds__(256) void layer_fused(const int* __restrict__ cols,
                                                   const int* __restrict__ deg,
                                                   const float* __restrict__ dinv,
                                                   const float* __restrict__ Xc,
                                                   const unsigned short* __restrict__ XH,
                                                   const unsigned short* __restrict__ PWh,
                                                   const unsigned short* __restrict__ PWl,
                                                   float* __restrict__ Xn,
                                                   unsigned short* __restrict__ oh,
                                                   const unsigned short* __restrict__ PDh,
                                                   const unsigned short* __restrict__ PDl,
                                                   const float* __restrict__ dec_b,
                                                   float* __restrict__ out) {
    __shared__ float Ybuf[16 * 264];                // 16.9 KB; two views
    float4* Ylds4 = (float4*)Ybuf;                  // [lr*64 + s] view
    int tid = threadIdx.x, wave = tid >> 6, lane = tid & 63;
    int bx = blockIdx.x;
    const float4* Xv = (const float4*)Xc;
    const ushort4* XHv = (const ushort4*)XH;

    // ---- phase 1: interleaved gather of 4 rows into LDS ----
    int   dcl[4];
    float di[4];
    int   c_pre[4];
    float w_pre[4];
    float4 acc[4];
#pragma unroll
    for (int rr = 0; rr < 4; ++rr) {
        int r = bx * 16 + wave * 4 + rr;            // < NN always (625*16=NN)
        dcl[rr] = deg[r];                           // pre-clamped <= 64
        di[rr]  = dinv[r];
        const int* crow = cols + (size_t)r * MAXDEG;
        int cp = (lane < dcl[rr]) ? crow[lane] : r;
        c_pre[rr] = cp;
        w_pre[rr] = dinv[cp];
        float4 xs = Xv[(size_t)r * 64 + lane];      // self term in f32
        acc[rr] = make_float4(di[rr] * xs.x, di[rr] * xs.y,
                              di[rr] * xs.z, di[rr] * xs.w);
    }
    int dmax = max(max(dcl[0], dcl[1]), max(dcl[2], dcl[3]));
    for (int j = 0; j < dmax; ++j) {
#pragma unroll
        for (int rr = 0; rr < 4; ++rr) {
            if (j < dcl[rr]) {                      // wave-uniform branch
                int c = __shfl(c_pre[rr], j);
                float w = __shfl(w_pre[rr], j);
                ushort4 xv = XHv[(size_t)c * 64 + lane];   // bf16 neighbor row
                acc[rr].x = fmaf(w, bf16_f32(xv.x), acc[rr].x);
                acc[rr].y = fmaf(w, bf16_f32(xv.y), acc[rr].y);
                acc[rr].z = fmaf(w, bf16_f32(xv.z), acc[rr].z);
                acc[rr].w = fmaf(w, bf16_f32(xv.w), acc[rr].w);
            }
        }
    }
#pragma unroll
    for (int rr = 0; rr < 4; ++rr) {
        int lr = wave * 4 + rr;
        float4 o = make_float4(di[rr] * acc[rr].x, di[rr] * acc[rr].y,
                               di[rr] * acc[rr].z, di[rr] * acc[rr].w);
        Ylds4[lr * 64 + (lane ^ (lr & 7))] = o;
    }
    __syncthreads();

    // ---- phase 2: GEMM 16x256 = Y(16x256) * Wm(256x256), bf16x3 ----
    int wc2 = wave;
    floatx4 acc2[4];
#pragma unroll
    for (int t = 0; t < 4; ++t) acc2[t] = (floatx4){0.f, 0.f, 0.f, 0.f};

#pragma unroll
    for (int ks = 0; ks < 8; ++ks) {
        int lr = lane & 15;
        int q = ks * 8 + ((lane >> 4) << 1);
        float4 fa = Ylds4[lr * 64 + (q ^ (lr & 7))];
        float4 fb = Ylds4[lr * 64 + ((q + 1) ^ (lr & 7))];
        float va[8] = {fa.x, fa.y, fa.z, fa.w, fb.x, fb.y, fb.z, fb.w};
        short8v a_h, a_l;
#pragma unroll
        for (int jj = 0; jj < 8; ++jj) {
            unsigned short h = bf16_rne(va[jj]);
            a_h[jj] = (short)h;
            a_l[jj] = (short)bf16_rne(va[jj] - bf16_f32(h));
        }
        const unsigned short* bph = PWh + ((size_t)(ks * 16 + wc2 * 4) * 64 + lane) * 8;
        const unsigned short* bpl = PWl + ((size_t)(ks * 16 + wc2 * 4) * 64 + lane) * 8;
#pragma unroll
        for (int t = 0; t < 4; ++t) {
            short8v b_h = *(const short8v*)(bph + t * 512);
            short8v b_l = *(const short8v*)(bpl + t * 512);
            acc2[t] = __builtin_amdgcn_mfma_f32_16x16x32_bf16(a_h, b_h, acc2[t], 0, 0, 0);
            acc2[t] = __builtin_amdgcn_mfma_f32_16x16x32_bf16(a_l, b_h, acc2[t], 0, 0, 0);
            acc2[t] = __builtin_amdgcn_mfma_f32_16x16x32_bf16(a_h, b_l, acc2[t], 0, 0, 0);
        }
    }

    // ---- epilogue ----
    int rb = bx * 16 + ((lane >> 4) << 2);
    int cb = wc2 * 64 + (lane & 15);
    if (DECF == 0) {
#pragma unroll
        for (int t = 0; t < 4; ++t) {
            int c = cb + t * 16;
#pragma unroll
            for (int i = 0; i < 4; ++i) {
                int r = rb + i;
                float v = acc2[t][i];
                float xv = Xc[(size_t)r * NHID + c];
                float o = xv + fmaxf(xv + v, 0.f);
                Xn[(size_t)r * NHID + c] = o;
                oh[(size_t)r * NHID + c] = bf16_rne(o);
            }
        }
    } else {
        __syncthreads();                            // phase-2 Ylds reads done
#pragma unroll
        for (int t = 0; t < 4; ++t) {
            int c = cb + t * 16;
#pragma unroll
            for (int i = 0; i < 4; ++i) {
                int rl = (rb + i) - bx * 16;        // local row 0..15
                float v = acc2[t][i];
                float xv = Xc[(size_t)(rb + i) * NHID + c];
                float o = xv + fmaxf(xv + v, 0.f);
                Ybuf[rl * 264 + c] = o;             // stage Xf tile (f32)
            }
        }
        __syncthreads();
        // decode: wave w (<3) computes cols w*16..w*16+15 for the 16 rows
        if (wave < 3) {
            int koff = (lane >> 4) << 3;
            floatx4 accd = (floatx4){0.f, 0.f, 0.f, 0.f};
#pragma unroll
            for (int ks = 0; ks < 8; ++ks) {
                const float* ap = &Ybuf[(lane & 15) * 264 + ks * 32 + koff];
                float4 f0 = *(const float4*)ap;
                float4 f1 = *(const float4*)(ap + 4);
                float va[8] = {f0.x, f0.y, f0.z, f0.w, f1.x, f1.y, f1.z, f1.w};
                short8v a_h, a_l;
#pragma unroll
                for (int jj = 0; jj < 8; ++jj) {
                    unsigned short h = bf16_rne(va[jj]);
                    a_h[jj] = (short)h;
                    a_l[jj] = (short)bf16_rne(va[jj] - bf16_f32(h));
                }
                const unsigned short* bph = PDh + ((size_t)(ks * 3 + wave) * 64 + lane) * 8;
                const unsigned short* bpl = PDl + ((size_t)(ks * 3 + wave) * 64 + lane) * 8;
                short8v b_h = *(const short8v*)bph;
                short8v b_l = *(const short8v*)bpl;
                accd = __builtin_amdgcn_mfma_f32_16x16x32_bf16(a_h, b_h, accd, 0, 0, 0);
                accd = __builtin_amdgcn_mfma_f32_16x16x32_bf16(a_l, b_h, accd, 0, 0, 0);
                accd = __builtin_amdgcn_mfma_f32_16x16x32_bf16(a_h, b_l, accd, 0, 0, 0);
            }
            int c = wave * 16 + (lane & 15);
            if (c < NCLASS) {
#pragma unroll
                for (int i = 0; i < 4; ++i) {
                    int r = rb + i;
                    out[(size_t)r * NCLASS + c] = accd[i] + dec_b[c];
                }
            }
        }
    }
}

// ---------------------------------------------------------------------------
extern "C" void kernel_launch(void* const* d_in, const int* in_sizes, int n_in,
                              void* d_out, int out_size, void* d_ws, size_t ws_size,
                              hipStream_t stream) {
    const float* x      = (const float*)d_in[0];
    const float* A      = (const float*)d_in[1];
    const float* enc_w  = (const float*)d_in[2];
    const float* enc_b  = (const float*)d_in[3];
    const float* conv_w = (const float*)d_in[4];
    const float* dec_w  = (const float*)d_in[5];
    const float* dec_b  = (const float*)d_in[6];
    float* out = (float*)d_out;

    char* w = (char*)d_ws;
    auto alloc = [&](size_t bytes) {
        char* p = w;
        w += (bytes + 255) & ~(size_t)255;
        return p;
    };
    int*            cols = (int*)alloc((size_t)NN * MAXDEG * 4);
    int*            deg  = (int*)alloc((size_t)NN * 4);
    float*          dinv = (float*)alloc((size_t)NN * 4);
    unsigned short* xh   = (unsigned short*)alloc((size_t)NN * NFEAT * 2);
    unsigned short* xl   = (unsigned short*)alloc((size_t)NN * NFEAT * 2);
    unsigned short* PEh  = (unsigned short*)alloc((size_t)NFEAT * NHID * 2);
    unsigned short* PEl  = (unsigned short*)alloc((size_t)NFEAT * NHID * 2);
    unsigned short* PWh  = (unsigned short*)alloc((size_t)NHID * NHID * 2);
    unsigned short* PWl  = (unsigned short*)alloc((size_t)NHID * NHID * 2);
    unsigned short* PDh  = (unsigned short*)alloc((size_t)NHID * 48 * 2);
    unsigned short* PDl  = (unsigned short*)alloc((size_t)NHID * 48 * 2);
    float*          Xa   = (float*)alloc((size_t)NN * NHID * 4);
    float*          Xb   = (float*)alloc((size_t)NN * NHID * 4);
    unsigned short* XHa  = (unsigned short*)alloc((size_t)NN * NHID * 2);
    unsigned short* XHb  = (unsigned short*)alloc((size_t)NN * NHID * 2);

    prep<<<5856, 256, 0, stream>>>(enc_w, conv_w, dec_w, x,
                                   PEh, PEl, PWh, PWl, PDh, PDl, xh, xl, deg);
    scan_upper<<<(NN + 3) / 4, 256, 0, stream>>>(A, cols, deg);
    enc_fin<<<668, 256, 0, stream>>>(xh, xl, PEh, PEl, enc_b, Xa, XHa, deg, dinv);

    float* Xcur = Xa;           unsigned short* XHcur = XHa;
    float* Xnxt = Xb;           unsigned short* XHnxt = XHb;
    for (int layer = 0; layer < 3; ++layer) {
        layer_fused<0><<<NN / 16, 256, 0, stream>>>(cols, deg, dinv, Xcur, XHcur,
                                                    PWh, PWl, Xnxt, XHnxt,
                                                    nullptr, nullptr, nullptr, nullptr);
        float* t = Xcur; Xcur = Xnxt; Xnxt = t;
        unsigned short* th = XHcur; XHcur = XHnxt; XHnxt = th;
    }
    layer_fused<1><<<NN / 16, 256, 0, stream>>>(cols, deg, dinv, Xcur, XHcur,
                                                PWh, PWl, nullptr, nullptr,
                                                PDh, PDl, dec_b, out);
}